// Round 5
// baseline (441.812 us; speedup 1.0000x reference)
//
#include <hip/hip_runtime.h>

#define N_SAMPLES 4096
#define D_IN      128
#define R_RULES   256
#define O_OUT     64
#define KPAD      136
#define NCHUNK    17
#define CH_I      8
#define NGROUPS   8
#define REP_V     8   // rep count for instrumented variants (scratch output)

typedef _Float16 f16;
typedef _Float16 f16x2 __attribute__((ext_vector_type(2)));
typedef _Float16 f16x4 __attribute__((ext_vector_type(4)));
typedef _Float16 f16x8 __attribute__((ext_vector_type(8)));
typedef float    f32x4 __attribute__((ext_vector_type(4)));

// ---------------------------------------------------------------------------
// Kernel 1: fused prep.  Blocks [0,1088): permute coeffs fp32 -> fp16 into
// TWO layouts: Cp (R0's LDS-bank-swizzled layout, used by the final main16)
// and Cp2 (lane-linear per 16-out tile: ((g*136+i)*4+wc)*512 + lane*8, used
// by the instrumented L2-direct variants).
// Blocks [1088,1216): build Bext (Markidis split) for the strengths GEMM.
// ---------------------------------------------------------------------------
__global__ __launch_bounds__(256) void anfis_prep_all(
    const float* __restrict__ coeffs, const float* __restrict__ centers,
    const float* __restrict__ sigmas, f16* __restrict__ Cp,
    f16* __restrict__ Cp2, f16* __restrict__ Bext) {
  __shared__ alignas(16) f16 T[64 * 32];
  __shared__ float red[4];
  const int bid = blockIdx.x;
  const int tid = threadIdx.x;

  if (bid < 1088) {
    const int g = bid / 136;
    const int i = bid - g * 136;
    const int rg = tid & 31;
    const int jb = tid >> 5;
    if (i < 129) {
      const float* src = coeffs + ((size_t)(g * 32 + rg) * 129 + i) * 64 + jb * 8;
      float4 a = reinterpret_cast<const float4*>(src)[0];
      float4 b = reinterpret_cast<const float4*>(src)[1];
      T[(jb * 8 + 0) * 32 + rg] = (f16)a.x;
      T[(jb * 8 + 1) * 32 + rg] = (f16)a.y;
      T[(jb * 8 + 2) * 32 + rg] = (f16)a.z;
      T[(jb * 8 + 3) * 32 + rg] = (f16)a.w;
      T[(jb * 8 + 4) * 32 + rg] = (f16)b.x;
      T[(jb * 8 + 5) * 32 + rg] = (f16)b.y;
      T[(jb * 8 + 6) * 32 + rg] = (f16)b.z;
      T[(jb * 8 + 7) * 32 + rg] = (f16)b.w;
    } else {
#pragma unroll
      for (int q = 0; q < 8; ++q) T[(jb * 8 + q) * 32 + rg] = (f16)0.0f;
    }
    __syncthreads();
    // Cp (swizzled, for final main16): tid -> (j = tid>>2, blk = tid&3)
    f16x8* dst = reinterpret_cast<f16x8*>(Cp + ((size_t)g * KPAD + i) * 2048);
    const int j = tid >> 2, blk = tid & 3;
    dst[(j << 2) | (blk ^ ((j >> 1) & 3))] = reinterpret_cast<const f16x8*>(T)[tid];
    // Cp2 (lane-linear for L2-direct variants): tid -> (wc = tid>>6, lane)
    f16x8* dst2 = reinterpret_cast<f16x8*>(Cp2 + (size_t)(g * 136 + i) * 2048);
    const int wc2 = tid >> 6, ln = tid & 63;
    const int q2 = ln >> 4, lm2 = ln & 15;
    dst2[wc2 * 64 + ln] = reinterpret_cast<const f16x8*>(T)[(wc2 * 16 + lm2) * 4 + q2];
  } else {
    const int sub = tid >> 7;
    const int d = tid & 127;
    const int r = ((bid - 1088) << 1) + sub;
    const float c = centers[(size_t)r * 128 + d];
    const float s = sigmas[(size_t)r * 128 + d];
    const float iv = 0.5f / (s * s);
    const float b1 = -iv;
    const float b2 = 2.0f * c * iv;
    f16 b1h = (f16)b1; f16 b1l = (f16)(b1 - (float)b1h);
    f16 b2h = (f16)b2; f16 b2l = (f16)(b2 - (float)b2h);
    auto put = [&](int k, f16 v) {
      Bext[((size_t)(k >> 3) * 256 + r) * 8 + (k & 7)] = v;
    };
    put(d, b1h);
    put(128 + d, b1l);
    put(256 + d, b1h);
    put(384 + d, b2h);
    put(512 + d, b2l);
    put(640 + d, b2h);
    float p = -c * c * iv;
#pragma unroll
    for (int off = 32; off; off >>= 1) p += __shfl_xor(p, off, 64);
    if ((tid & 63) == 0) red[tid >> 6] = p;
    __syncthreads();
    if (d < 30) put(770 + d, (f16)0.0f);
    if (d == 0) {
      float k2 = red[sub * 2] + red[sub * 2 + 1];
      f16 h = (f16)k2; f16 l = (f16)(k2 - (float)h);
      put(768, h);
      put(769, l);
    }
  }
}

// ---------------------------------------------------------------------------
// Kernel 2 (unchanged): strengths + normalization fused.
// ---------------------------------------------------------------------------
__global__ __launch_bounds__(512) void anfis_s16n(
    const float* __restrict__ X, const f16* __restrict__ Bext,
    f16* __restrict__ P) {
  __shared__ alignas(16) f16 Xq[16 * 512];
  __shared__ float rowsum[16][8];
  const int tid = threadIdx.x;
  const int m0 = blockIdx.x * 16;
  const int w = tid >> 6, lane = tid & 63;
  const int lm = lane & 15, quad = lane >> 4;

  if (tid < 256) {
    int m = tid >> 4, oct = tid & 15;
    const float* src = X + (size_t)(m0 + m) * 128 + oct * 8;
    float4 a = reinterpret_cast<const float4*>(src)[0];
    float4 b = reinterpret_cast<const float4*>(src)[1];
    float xs[8] = {a.x, a.y, a.z, a.w, b.x, b.y, b.z, b.w};
    f16x8 vh, vl, v2h, v2l;
#pragma unroll
    for (int q = 0; q < 8; ++q) {
      float x = xs[q];
      f16 h = (f16)x;   f16 l = (f16)(x - (float)h);
      float x2 = x * x;
      f16 h2 = (f16)x2; f16 l2 = (f16)(x2 - (float)h2);
      vh[q] = h; vl[q] = l; v2h[q] = h2; v2l[q] = l2;
    }
    f16x8* row = reinterpret_cast<f16x8*>(&Xq[m * 512]);
    int sw = m & 7;
    row[(0 * 16 + oct) ^ sw] = v2h;
    row[(1 * 16 + oct) ^ sw] = v2l;
    row[(2 * 16 + oct) ^ sw] = vh;
    row[(3 * 16 + oct) ^ sw] = vl;
  }
  __syncthreads();

  f32x4 acc[2] = {};
  const f16x8* arow = reinterpret_cast<const f16x8*>(&Xq[lm * 512]);
  const int asw = lm & 7;
  const int col0 = w * 32 + lm;

#pragma unroll
  for (int t = 0; t < 24; ++t) {
    const int seg = t >> 2;
    const int plane = (seg < 2) ? 0 : (seg == 2) ? 1 : (seg < 5) ? 2 : 3;
    const int o = t * 4 + quad;
    f16x8 av = arow[(plane * 16 + (o & 15)) ^ asw];
    const f16* bp = Bext + ((size_t)o * 256 + col0) * 8;
    f16x8 b0 = *reinterpret_cast<const f16x8*>(bp);
    f16x8 b1 = *reinterpret_cast<const f16x8*>(bp + 16 * 8);
    acc[0] = __builtin_amdgcn_mfma_f32_16x16x32_f16(av, b0, acc[0], 0, 0, 0);
    acc[1] = __builtin_amdgcn_mfma_f32_16x16x32_f16(av, b1, acc[1], 0, 0, 0);
  }
  {
    f16x8 av = {};
    if (quad == 0) { av[0] = (f16)1.0f; av[1] = (f16)1.0f; }
    const int o = 96 + quad;
    const f16* bp = Bext + ((size_t)o * 256 + col0) * 8;
    f16x8 b0 = *reinterpret_cast<const f16x8*>(bp);
    f16x8 b1 = *reinterpret_cast<const f16x8*>(bp + 16 * 8);
    acc[0] = __builtin_amdgcn_mfma_f32_16x16x32_f16(av, b0, acc[0], 0, 0, 0);
    acc[1] = __builtin_amdgcn_mfma_f32_16x16x32_f16(av, b1, acc[1], 0, 0, 0);
  }

  float e[2][4];
#pragma unroll
  for (int nf = 0; nf < 2; ++nf)
#pragma unroll
    for (int q = 0; q < 4; ++q) e[nf][q] = __expf(acc[nf][q]);

  float rp[4];
#pragma unroll
  for (int q = 0; q < 4; ++q) {
    rp[q] = e[0][q] + e[1][q];
#pragma unroll
    for (int msk = 1; msk < 16; msk <<= 1) rp[q] += __shfl_xor(rp[q], msk, 64);
  }
  if (lm == 0)
#pragma unroll
    for (int q = 0; q < 4; ++q) rowsum[quad * 4 + q][w] = rp[q];
  __syncthreads();

#pragma unroll
  for (int q = 0; q < 4; ++q) {
    const int row = quad * 4 + q;
    float s8 = 0.f;
#pragma unroll
    for (int w2 = 0; w2 < 8; ++w2) s8 += rowsum[row][w2];
    const float inv = 1.0f / (s8 + 1e-8f);
#pragma unroll
    for (int nf = 0; nf < 2; ++nf)
      P[(size_t)(m0 + row) * R_RULES + w * 32 + nf * 16 + lm] =
          (f16)(e[nf][q] * inv);
  }
}

// ---------------------------------------------------------------------------
// VARIANT B (instrumented, REP_V reps, scratch output): L2-direct B with
// lane-linear Cp2 loads + explicit register double-buffer one chunk ahead.
// Wave tile 64 rows x 16 cols; 256 thr; grid 512 = 2 blocks/CU.
// ---------------------------------------------------------------------------
__global__ __launch_bounds__(256) void anfis_k3B(
    const float* __restrict__ X, const f16* __restrict__ P,
    const f16* __restrict__ Cp2, float* __restrict__ outp) {
  __shared__ alignas(16) f16 Xs[64 * KPAD];
  const int tid = threadIdx.x;
  const int g = blockIdx.x & 7;
  const int m0 = (blockIdx.x >> 3) * 64;
  const int wc = tid >> 6, lane = tid & 63;
  const int lm = lane & 15, quad = lane >> 4;
  union F8 { f16x8 v; f16x2 h[4]; };

  for (int rep = 0; rep < REP_V; ++rep) {
    asm volatile("" ::: "memory");
#pragma unroll
    for (int it = 0; it < 8; ++it) {
      int fi = tid + (it << 8);
      int m = fi >> 5, k4 = (fi & 31) << 2;
      float4 v = reinterpret_cast<const float4*>(X)[(size_t)(m0 + m) * 32 + (fi & 31)];
      f16x4 h = {(f16)v.x, (f16)v.y, (f16)v.z, (f16)v.w};
      *reinterpret_cast<f16x4*>(&Xs[m * KPAD + k4]) = h;
    }
    if (tid < 64) {
      f16x8 bias = {};
      bias[0] = (f16)1.0f;
      *reinterpret_cast<f16x8*>(&Xs[tid * KPAD + 128]) = bias;
    }
    F8 pf[4];
#pragma unroll
    for (int mf = 0; mf < 4; ++mf) {
      int row = m0 + mf * 16 + lm;
      pf[mf].v = *reinterpret_cast<const f16x8*>(
          &P[(size_t)row * R_RULES + g * 32 + quad * 8]);
    }
    __syncthreads();

    // lane-linear: per (g,i,wc) the wave's 64x16B are contiguous (1KB burst)
    const f16* bp = Cp2 + (size_t)(g * 136) * 2048 + wc * 512 + lane * 8;
    f16x8 bbuf[8];
#pragma unroll
    for (int ii = 0; ii < 8; ++ii)
      bbuf[ii] = *reinterpret_cast<const f16x8*>(bp + (size_t)ii * 2048);

    f32x4 acc[4] = {};
    for (int c = 0; c < NCHUNK; ++c) {
      f16x8 xv[4];
#pragma unroll
      for (int mf = 0; mf < 4; ++mf)
        xv[mf] = *reinterpret_cast<const f16x8*>(
            &Xs[(mf * 16 + lm) * KPAD + c * 8]);
      const f16* bnext = bp + (size_t)((c + 1 < NCHUNK ? c + 1 : 0) * 8) * 2048;
#pragma unroll
      for (int ii = 0; ii < 8; ++ii) {
        f16x8 b0 = bbuf[ii];
        bbuf[ii] = *reinterpret_cast<const f16x8*>(bnext + (size_t)ii * 2048);
#pragma unroll
        for (int mf = 0; mf < 4; ++mf) {
          f16 xvv = xv[mf][ii];
          f16x2 xd = {xvv, xvv};
          F8 a;
          a.h[0] = pf[mf].h[0] * xd;
          a.h[1] = pf[mf].h[1] * xd;
          a.h[2] = pf[mf].h[2] * xd;
          a.h[3] = pf[mf].h[3] * xd;
          acc[mf] = __builtin_amdgcn_mfma_f32_16x16x32_f16(a.v, b0, acc[mf], 0, 0, 0);
        }
      }
    }
#pragma unroll
    for (int mf = 0; mf < 4; ++mf)
#pragma unroll
      for (int q = 0; q < 4; ++q) {
        int row = m0 + mf * 16 + quad * 4 + q;
        int col = wc * 16 + lm;
        outp[((size_t)g * N_SAMPLES + row) * O_OUT + col] = acc[mf][q];
      }
    __syncthreads();
  }
}

// ---------------------------------------------------------------------------
// VARIANT C (instrumented, REP_V reps, scratch output): like B but 128-row
// wave tiles (8 m-frags) -> half the L2 B-traffic, 1 wave/SIMD, bets on
// per-wave ILP (8 MFMA + 1 load per inner iter).  grid 256 = 1 block/CU.
// ---------------------------------------------------------------------------
__global__ __launch_bounds__(256, 1) void anfis_k3C(
    const float* __restrict__ X, const f16* __restrict__ P,
    const f16* __restrict__ Cp2, float* __restrict__ outp) {
  __shared__ alignas(16) f16 Xs[128 * KPAD];
  const int tid = threadIdx.x;
  const int g = blockIdx.x & 7;
  const int m0 = (blockIdx.x >> 3) * 128;
  const int wc = tid >> 6, lane = tid & 63;
  const int lm = lane & 15, quad = lane >> 4;
  union F8 { f16x8 v; f16x2 h[4]; };

  for (int rep = 0; rep < REP_V; ++rep) {
    asm volatile("" ::: "memory");
#pragma unroll
    for (int it = 0; it < 16; ++it) {
      int fi = tid + (it << 8);
      int m = fi >> 5, k4 = (fi & 31) << 2;
      float4 v = reinterpret_cast<const float4*>(X)[(size_t)(m0 + m) * 32 + (fi & 31)];
      f16x4 h = {(f16)v.x, (f16)v.y, (f16)v.z, (f16)v.w};
      *reinterpret_cast<f16x4*>(&Xs[m * KPAD + k4]) = h;
    }
    if (tid < 128) {
      f16x8 bias = {};
      bias[0] = (f16)1.0f;
      *reinterpret_cast<f16x8*>(&Xs[tid * KPAD + 128]) = bias;
    }
    F8 pf[8];
#pragma unroll
    for (int mf = 0; mf < 8; ++mf) {
      int row = m0 + mf * 16 + lm;
      pf[mf].v = *reinterpret_cast<const f16x8*>(
          &P[(size_t)row * R_RULES + g * 32 + quad * 8]);
    }
    __syncthreads();

    const f16* bp = Cp2 + (size_t)(g * 136) * 2048 + wc * 512 + lane * 8;
    f16x8 bbuf[8];
#pragma unroll
    for (int ii = 0; ii < 8; ++ii)
      bbuf[ii] = *reinterpret_cast<const f16x8*>(bp + (size_t)ii * 2048);

    f32x4 acc[8] = {};
    for (int c = 0; c < NCHUNK; ++c) {
      f16x8 xv[8];
#pragma unroll
      for (int mf = 0; mf < 8; ++mf)
        xv[mf] = *reinterpret_cast<const f16x8*>(
            &Xs[(mf * 16 + lm) * KPAD + c * 8]);
      const f16* bnext = bp + (size_t)((c + 1 < NCHUNK ? c + 1 : 0) * 8) * 2048;
#pragma unroll
      for (int ii = 0; ii < 8; ++ii) {
        f16x8 b0 = bbuf[ii];
        bbuf[ii] = *reinterpret_cast<const f16x8*>(bnext + (size_t)ii * 2048);
#pragma unroll
        for (int mf = 0; mf < 8; ++mf) {
          f16 xvv = xv[mf][ii];
          f16x2 xd = {xvv, xvv};
          F8 a;
          a.h[0] = pf[mf].h[0] * xd;
          a.h[1] = pf[mf].h[1] * xd;
          a.h[2] = pf[mf].h[2] * xd;
          a.h[3] = pf[mf].h[3] * xd;
          acc[mf] = __builtin_amdgcn_mfma_f32_16x16x32_f16(a.v, b0, acc[mf], 0, 0, 0);
        }
      }
    }
#pragma unroll
    for (int mf = 0; mf < 8; ++mf)
#pragma unroll
      for (int q = 0; q < 4; ++q) {
        int row = m0 + mf * 16 + quad * 4 + q;
        int col = wc * 16 + lm;
        outp[((size_t)g * N_SAMPLES + row) * O_OUT + col] = acc[mf][q];
      }
    __syncthreads();
  }
}

// ---------------------------------------------------------------------------
// Kernel 3 FINAL (R0 verbatim, proven 102.4us path): LDS-staged + swizzle.
// ---------------------------------------------------------------------------
__global__ __launch_bounds__(256) void anfis_main16(
    const float* __restrict__ X, const f16* __restrict__ P,
    const f16* __restrict__ Cp, float* __restrict__ part) {
  __shared__ alignas(16) f16 Xs[64 * KPAD];
  __shared__ alignas(16) f16 Bs[CH_I * 64 * 32];
  const int tid = threadIdx.x;
  const int g = blockIdx.x & 7;
  const int m0 = (blockIdx.x >> 3) * 64;
  const int w = tid >> 6, lane = tid & 63;
  const int mg = w >> 1, ng = w & 1;
  const int lm = lane & 15, quad = lane >> 4;

#pragma unroll
  for (int it = 0; it < 8; ++it) {
    int fi = tid + (it << 8);
    int m = fi >> 5, k4 = (fi & 31) << 2;
    float4 v = reinterpret_cast<const float4*>(X)[(size_t)(m0 + m) * 32 + (fi & 31)];
    f16x4 h = {(f16)v.x, (f16)v.y, (f16)v.z, (f16)v.w};
    *reinterpret_cast<f16x4*>(&Xs[m * KPAD + k4]) = h;
  }
  if (tid < 64) {
    f16x8 bias = {};
    bias[0] = (f16)1.0f;
    *reinterpret_cast<f16x8*>(&Xs[tid * KPAD + 128]) = bias;
  }

  union F8 { f16x8 v; f16x2 h[4]; };
  F8 pf[2];
#pragma unroll
  for (int mf = 0; mf < 2; ++mf) {
    int row = m0 + mg * 32 + mf * 16 + lm;
    pf[mf].v = *reinterpret_cast<const f16x8*>(
        &P[(size_t)row * R_RULES + g * 32 + quad * 8]);
  }

  f32x4 acc[2][2] = {};
  const char* cpg = (const char*)Cp + (size_t)g * KPAD * 4096;
  const int bswz = (quad ^ ((lm >> 1) & 3)) * 8;

  for (int c = 0; c < NCHUNK; ++c) {
    __syncthreads();
    const char* gsrc = cpg + (size_t)c * 32768;
#pragma unroll
    for (int it = 0; it < 8; ++it) {
      int off = (it << 12) + (w << 10);
      __builtin_amdgcn_global_load_lds(
          (const __attribute__((address_space(1))) unsigned int*)(gsrc + off + lane * 16),
          (__attribute__((address_space(3))) unsigned int*)((char*)Bs + off),
          16, 0, 0);
    }
    __syncthreads();
    f16x8 xv[2];
    xv[0] = *reinterpret_cast<const f16x8*>(&Xs[(mg * 32 + lm) * KPAD + c * 8]);
    xv[1] = *reinterpret_cast<const f16x8*>(&Xs[(mg * 32 + 16 + lm) * KPAD + c * 8]);
#pragma unroll
    for (int ii = 0; ii < CH_I; ++ii) {
      F8 a[2];
#pragma unroll
      for (int mf = 0; mf < 2; ++mf) {
        f16 xvv = xv[mf][ii];
        f16x2 xd = {xvv, xvv};
        a[mf].h[0] = pf[mf].h[0] * xd;
        a[mf].h[1] = pf[mf].h[1] * xd;
        a[mf].h[2] = pf[mf].h[2] * xd;
        a[mf].h[3] = pf[mf].h[3] * xd;
      }
      const f16* brow = &Bs[(ii * 64 + ng * 32 + lm) * 32 + bswz];
      f16x8 b0 = *reinterpret_cast<const f16x8*>(brow);
      f16x8 b1 = *reinterpret_cast<const f16x8*>(brow + 16 * 32);
      acc[0][0] = __builtin_amdgcn_mfma_f32_16x16x32_f16(a[0].v, b0, acc[0][0], 0, 0, 0);
      acc[0][1] = __builtin_amdgcn_mfma_f32_16x16x32_f16(a[0].v, b1, acc[0][1], 0, 0, 0);
      acc[1][0] = __builtin_amdgcn_mfma_f32_16x16x32_f16(a[1].v, b0, acc[1][0], 0, 0, 0);
      acc[1][1] = __builtin_amdgcn_mfma_f32_16x16x32_f16(a[1].v, b1, acc[1][1], 0, 0, 0);
    }
  }

#pragma unroll
  for (int mf = 0; mf < 2; ++mf)
#pragma unroll
    for (int nf = 0; nf < 2; ++nf)
#pragma unroll
      for (int q = 0; q < 4; ++q) {
        int row = m0 + mg * 32 + mf * 16 + quad * 4 + q;
        int col = ng * 32 + nf * 16 + lm;
        part[((size_t)g * N_SAMPLES + row) * O_OUT + col] = acc[mf][nf][q];
      }
}

// ---------------------------------------------------------------------------
// Kernel 4 (unchanged): sum 8 group partials + softmax over 64 outputs.
// ---------------------------------------------------------------------------
__global__ __launch_bounds__(256) void anfis_out(
    const float* __restrict__ part, float* __restrict__ out) {
  const int n = blockIdx.x * 4 + (threadIdx.x >> 6);
  const int lane = threadIdx.x & 63;
  const size_t stride = (size_t)N_SAMPLES * O_OUT;
  const float* p0 = part + (size_t)n * O_OUT + lane;
  float v = 0.f;
#pragma unroll
  for (int gg = 0; gg < 8; ++gg) v += p0[gg * stride];
  float mx = v;
#pragma unroll
  for (int off = 32; off; off >>= 1) mx = fmaxf(mx, __shfl_xor(mx, off, 64));
  float e = __expf(v - mx);
  float s = e;
#pragma unroll
  for (int off = 32; off; off >>= 1) s += __shfl_xor(s, off, 64);
  out[(size_t)n * O_OUT + lane] = e / s;
}

extern "C" void kernel_launch(void* const* d_in, const int* in_sizes, int n_in,
                              void* d_out, int out_size, void* d_ws, size_t ws_size,
                              hipStream_t stream) {
  const float* X       = (const float*)d_in[0];
  const float* centers = (const float*)d_in[1];
  const float* sigmas  = (const float*)d_in[2];
  const float* coeffs  = (const float*)d_in[3];
  float* out = (float*)d_out;

  float* part = (float*)d_ws;                                     // 8 MB
  f16*   Cp   = (f16*)(part + (size_t)NGROUPS * N_SAMPLES * O_OUT);
  f16*   Cp2  = Cp + (size_t)NGROUPS * KPAD * 2048;               // 4.46 MB
  f16*   Bext = Cp2 + (size_t)NGROUPS * KPAD * 2048;              // 400 KB
  f16*   P    = Bext + (size_t)100 * 256 * 8;                     // 2 MB
  float* scratch = (float*)(P + (size_t)N_SAMPLES * R_RULES);     // 8 MB

  anfis_prep_all<<<1088 + 128, 256, 0, stream>>>(coeffs, centers, sigmas, Cp, Cp2, Bext);
  anfis_s16n<<<N_SAMPLES / 16, 512, 0, stream>>>(X, Bext, P);
  anfis_k3B<<<512, 256, 0, stream>>>(X, P, Cp2, scratch);   // instrumented A/B
  anfis_k3C<<<256, 256, 0, stream>>>(X, P, Cp2, scratch);   // instrumented A/B
  anfis_main16<<<512, 256, 0, stream>>>(X, P, Cp, part);    // final (correct) path
  anfis_out<<<N_SAMPLES / 4, 256, 0, stream>>>(part, out);
}

// Round 6
// 106.902 us; speedup vs baseline: 4.1328x; 4.1328x over previous
//
#include <hip/hip_runtime.h>

#define N_SAMPLES 4096
#define D_IN      128
#define R_RULES   256
#define O_OUT     64
#define KPAD      136
#define NG16      16     // 16 rule-groups of 16 rules (K=16 per MFMA)
#define CP3_I     144    // padded i-slots per group in Cp3

typedef _Float16 f16;
typedef _Float16 f16x2 __attribute__((ext_vector_type(2)));
typedef _Float16 f16x4 __attribute__((ext_vector_type(4)));
typedef _Float16 f16x8 __attribute__((ext_vector_type(8)));
typedef float    f32x4 __attribute__((ext_vector_type(4)));
typedef float    f32x16 __attribute__((ext_vector_type(16)));

// ---------------------------------------------------------------------------
// Kernel 1: fused prep.  Blocks [0,1088): permute coeffs fp32 -> fp16 into
// Cp3[g16][i][jh][rh][j32] (f16x8 granules): per i-slot 2048B holding
// B-fragments for mfma_32x32x16 -- lane l reads col j=l&31, rule-octet
// rh=l>>5 as one f16x8.  Layout is linear-copy stageable via global_load_lds
// and the per-(i,jh) 1KB block is read half-wave-linear (conflict-free).
// Blocks [1088,1216): build Bext (Markidis split) for the strengths GEMM.
// ---------------------------------------------------------------------------
__global__ __launch_bounds__(256) void anfis_prep_all(
    const float* __restrict__ coeffs, const float* __restrict__ centers,
    const float* __restrict__ sigmas, f16* __restrict__ Cp3,
    f16* __restrict__ Bext) {
  __shared__ alignas(16) f16 T[64 * 32];
  __shared__ float red[4];
  const int bid = blockIdx.x;
  const int tid = threadIdx.x;

  if (bid < 1088) {
    const int g8 = bid / 136;          // old 32-rule group
    const int i = bid - g8 * 136;
    const int rg = tid & 31;
    const int jb = tid >> 5;
    if (i < 129) {
      const float* src = coeffs + ((size_t)(g8 * 32 + rg) * 129 + i) * 64 + jb * 8;
      float4 a = reinterpret_cast<const float4*>(src)[0];
      float4 b = reinterpret_cast<const float4*>(src)[1];
      T[(jb * 8 + 0) * 32 + rg] = (f16)a.x;
      T[(jb * 8 + 1) * 32 + rg] = (f16)a.y;
      T[(jb * 8 + 2) * 32 + rg] = (f16)a.z;
      T[(jb * 8 + 3) * 32 + rg] = (f16)a.w;
      T[(jb * 8 + 4) * 32 + rg] = (f16)b.x;
      T[(jb * 8 + 5) * 32 + rg] = (f16)b.y;
      T[(jb * 8 + 6) * 32 + rg] = (f16)b.z;
      T[(jb * 8 + 7) * 32 + rg] = (f16)b.w;
    } else {
#pragma unroll
      for (int q = 0; q < 8; ++q) T[(jb * 8 + q) * 32 + rg] = (f16)0.0f;
    }
    __syncthreads();
    // tid -> (j = tid>>2, oc = tid&3): rule-octet oc of the 32-rule group.
    // global rule r = g8*32 + oc*8 + e -> g16 = g8*2 + (oc>>1), rh = oc&1.
    const int j = tid >> 2, oc = tid & 3;
    const int g16 = g8 * 2 + (oc >> 1), rh = oc & 1;
    const int jh = j >> 5, jl = j & 31;
    f16x8* dst3 = reinterpret_cast<f16x8*>(Cp3);
    dst3[(((size_t)g16 * CP3_I + i) * 2 + jh) * 64 + rh * 32 + jl] =
        *reinterpret_cast<const f16x8*>(&T[j * 32 + oc * 8]);
  } else {
    const int sub = tid >> 7;
    const int d = tid & 127;
    const int r = ((bid - 1088) << 1) + sub;
    const float c = centers[(size_t)r * 128 + d];
    const float s = sigmas[(size_t)r * 128 + d];
    const float iv = 0.5f / (s * s);
    const float b1 = -iv;
    const float b2 = 2.0f * c * iv;
    f16 b1h = (f16)b1; f16 b1l = (f16)(b1 - (float)b1h);
    f16 b2h = (f16)b2; f16 b2l = (f16)(b2 - (float)b2h);
    auto put = [&](int k, f16 v) {
      Bext[((size_t)(k >> 3) * 256 + r) * 8 + (k & 7)] = v;
    };
    put(d, b1h);
    put(128 + d, b1l);
    put(256 + d, b1h);
    put(384 + d, b2h);
    put(512 + d, b2l);
    put(640 + d, b2h);
    float p = -c * c * iv;
#pragma unroll
    for (int off = 32; off; off >>= 1) p += __shfl_xor(p, off, 64);
    if ((tid & 63) == 0) red[tid >> 6] = p;
    __syncthreads();
    if (d < 30) put(770 + d, (f16)0.0f);
    if (d == 0) {
      float k2 = red[sub * 2] + red[sub * 2 + 1];
      f16 h = (f16)k2; f16 l = (f16)(k2 - (float)h);
      put(768, h);
      put(769, l);
    }
  }
}

// ---------------------------------------------------------------------------
// Kernel 2 (unchanged): strengths + normalization fused.
// ---------------------------------------------------------------------------
__global__ __launch_bounds__(512) void anfis_s16n(
    const float* __restrict__ X, const f16* __restrict__ Bext,
    f16* __restrict__ P) {
  __shared__ alignas(16) f16 Xq[16 * 512];
  __shared__ float rowsum[16][8];
  const int tid = threadIdx.x;
  const int m0 = blockIdx.x * 16;
  const int w = tid >> 6, lane = tid & 63;
  const int lm = lane & 15, quad = lane >> 4;

  if (tid < 256) {
    int m = tid >> 4, oct = tid & 15;
    const float* src = X + (size_t)(m0 + m) * 128 + oct * 8;
    float4 a = reinterpret_cast<const float4*>(src)[0];
    float4 b = reinterpret_cast<const float4*>(src)[1];
    float xs[8] = {a.x, a.y, a.z, a.w, b.x, b.y, b.z, b.w};
    f16x8 vh, vl, v2h, v2l;
#pragma unroll
    for (int q = 0; q < 8; ++q) {
      float x = xs[q];
      f16 h = (f16)x;   f16 l = (f16)(x - (float)h);
      float x2 = x * x;
      f16 h2 = (f16)x2; f16 l2 = (f16)(x2 - (float)h2);
      vh[q] = h; vl[q] = l; v2h[q] = h2; v2l[q] = l2;
    }
    f16x8* row = reinterpret_cast<f16x8*>(&Xq[m * 512]);
    int sw = m & 7;
    row[(0 * 16 + oct) ^ sw] = v2h;
    row[(1 * 16 + oct) ^ sw] = v2l;
    row[(2 * 16 + oct) ^ sw] = vh;
    row[(3 * 16 + oct) ^ sw] = vl;
  }
  __syncthreads();

  f32x4 acc[2] = {};
  const f16x8* arow = reinterpret_cast<const f16x8*>(&Xq[lm * 512]);
  const int asw = lm & 7;
  const int col0 = w * 32 + lm;

#pragma unroll
  for (int t = 0; t < 24; ++t) {
    const int seg = t >> 2;
    const int plane = (seg < 2) ? 0 : (seg == 2) ? 1 : (seg < 5) ? 2 : 3;
    const int o = t * 4 + quad;
    f16x8 av = arow[(plane * 16 + (o & 15)) ^ asw];
    const f16* bp = Bext + ((size_t)o * 256 + col0) * 8;
    f16x8 b0 = *reinterpret_cast<const f16x8*>(bp);
    f16x8 b1 = *reinterpret_cast<const f16x8*>(bp + 16 * 8);
    acc[0] = __builtin_amdgcn_mfma_f32_16x16x32_f16(av, b0, acc[0], 0, 0, 0);
    acc[1] = __builtin_amdgcn_mfma_f32_16x16x32_f16(av, b1, acc[1], 0, 0, 0);
  }
  {
    f16x8 av = {};
    if (quad == 0) { av[0] = (f16)1.0f; av[1] = (f16)1.0f; }
    const int o = 96 + quad;
    const f16* bp = Bext + ((size_t)o * 256 + col0) * 8;
    f16x8 b0 = *reinterpret_cast<const f16x8*>(bp);
    f16x8 b1 = *reinterpret_cast<const f16x8*>(bp + 16 * 8);
    acc[0] = __builtin_amdgcn_mfma_f32_16x16x32_f16(av, b0, acc[0], 0, 0, 0);
    acc[1] = __builtin_amdgcn_mfma_f32_16x16x32_f16(av, b1, acc[1], 0, 0, 0);
  }

  float e[2][4];
#pragma unroll
  for (int nf = 0; nf < 2; ++nf)
#pragma unroll
    for (int q = 0; q < 4; ++q) e[nf][q] = __expf(acc[nf][q]);

  float rp[4];
#pragma unroll
  for (int q = 0; q < 4; ++q) {
    rp[q] = e[0][q] + e[1][q];
#pragma unroll
    for (int msk = 1; msk < 16; msk <<= 1) rp[q] += __shfl_xor(rp[q], msk, 64);
  }
  if (lm == 0)
#pragma unroll
    for (int q = 0; q < 4; ++q) rowsum[quad * 4 + q][w] = rp[q];
  __syncthreads();

#pragma unroll
  for (int q = 0; q < 4; ++q) {
    const int row = quad * 4 + q;
    float s8 = 0.f;
#pragma unroll
    for (int w2 = 0; w2 < 8; ++w2) s8 += rowsum[row][w2];
    const float inv = 1.0f / (s8 + 1e-8f);
#pragma unroll
    for (int nf = 0; nf < 2; ++nf)
      P[(size_t)(m0 + row) * R_RULES + w * 32 + nf * 16 + lm] =
          (f16)(e[nf][q] * inv);
  }
}

// ---------------------------------------------------------------------------
// Kernel 3 v6: rules GEMM on mfma_f32_32x32x16_f16.
// Why: with 16x16x32, each 4.85cy MFMA needed 8cy of pk_mul + 12cy of LDS B
// -> structurally non-matrix-bound (R5 A/B: 18-24us, MfmaUtil 33%).  32x32x16
// doubles flops/instr (33.8cy/SIMD) at the SAME a-frag (4 pk_mul) and SAME
// 1KB B-frag -> non-matrix ~25cy < 33.8cy: matrix-bound without reuse tricks.
//  - 16 rule-groups (K=16/MFMA), wave = one 32x32 output tile.
//  - 512 thr / 8 waves = 4 m-slices x 2 j-halves -> block 128 rows x 64 cols.
//  - grid 512 = 32 m-blocks x 16 groups = 2 blocks/CU, 4 waves/SIMD.
//  - B: LDS dbuf, 16-i chunks (32KB), staged via global_load_lds (4x8KB),
//    stage(next) issued before compute(cur), one barrier per chunk.
//  - X: in registers, 2xf16x8 per chunk, global-prefetched one chunk ahead.
//  - fully unrolled -> all xb/buf indices compile-time (no scratch).
//  - i=128 bias tail: A = pf directly (X=1), single MFMA; i>128 skipped
//    exactly (B rows are zero there).
// ---------------------------------------------------------------------------
__global__ __launch_bounds__(512, 4) void anfis_rules32(
    const float* __restrict__ X, const f16* __restrict__ P,
    const f16* __restrict__ Cp3, float* __restrict__ part) {
  __shared__ alignas(16) f16 Bs[2 * 16384];   // 2 x 32KB dbuf
  const int tid = threadIdx.x;
  const int g = blockIdx.x & 15;
  const int m0 = (blockIdx.x >> 4) * 128;
  const int w = tid >> 6, lane = tid & 63;
  const int ms = w >> 1, jh = w & 1;
  const int jl = lane & 31, rh = lane >> 5;
  const int arow = m0 + ms * 32 + jl;   // A-operand row for this lane

  union F8 { f16x8 v; f16x2 h[4]; };
  F8 pf;   // P[arow, g*16 + rh*8 .. +8]
  pf.v = *reinterpret_cast<const f16x8*>(&P[(size_t)arow * R_RULES + g * 16 + rh * 8]);

  const float4* Xrow = reinterpret_cast<const float4*>(X + (size_t)arow * D_IN);
  const char* cg = (const char*)Cp3 + (size_t)g * (CP3_I * 2048);
  // LDS read offset (f16 units) inside an i-slot: [jh][rh][jl] halves
  const int rdoff = jh * 512 + rh * 256 + jl * 8;

  auto stage = [&](int buf, int ch) {
    const char* gsrc = cg + (size_t)ch * 32768;
#pragma unroll
    for (int r = 0; r < 4; ++r) {
      int off = (r << 13) + (w << 10);
      __builtin_amdgcn_global_load_lds(
          (const __attribute__((address_space(1))) unsigned int*)(gsrc + off + lane * 16),
          (__attribute__((address_space(3))) unsigned int*)((char*)Bs + buf * 32768 + off),
          16, 0, 0);
    }
  };

  f16x8 xb[2][2];
  auto cvt16 = [](float4 a, float4 b) {
    f16x8 r = {(f16)a.x, (f16)a.y, (f16)a.z, (f16)a.w,
               (f16)b.x, (f16)b.y, (f16)b.z, (f16)b.w};
    return r;
  };

  // prologue: stage chunk 0, load X chunk 0
  stage(0, 0);
  {
    float4 f0 = Xrow[0], f1 = Xrow[1], f2 = Xrow[2], f3 = Xrow[3];
    xb[0][0] = cvt16(f0, f1);
    xb[0][1] = cvt16(f2, f3);
  }
  __syncthreads();   // chunk 0 staged

  f32x16 acc = {};
#pragma unroll
  for (int ch = 0; ch < 8; ++ch) {
    float4 f0, f1, f2, f3;
    if (ch < 7) {
      stage((ch + 1) & 1, ch + 1);           // async, in flight over compute
      f0 = Xrow[(ch + 1) * 4 + 0];
      f1 = Xrow[(ch + 1) * 4 + 1];
      f2 = Xrow[(ch + 1) * 4 + 2];
      f3 = Xrow[(ch + 1) * 4 + 3];
    } else {
      // tail stage: i=128 only (2KB) into buf 0
      if (tid < 128) {
        const char* gsrc = cg + (size_t)8 * 32768;
        int off = (tid >> 6) << 10;
        __builtin_amdgcn_global_load_lds(
            (const __attribute__((address_space(1))) unsigned int*)(gsrc + off + lane * 16),
            (__attribute__((address_space(3))) unsigned int*)((char*)Bs + off),
            16, 0, 0);
      }
    }
    const f16* bb = Bs + (ch & 1) * 16384;
#pragma unroll
    for (int t = 0; t < 16; ++t) {
      f16 xs = xb[ch & 1][t >> 3][t & 7];
      f16x2 xd = {xs, xs};
      F8 a;
      a.h[0] = pf.h[0] * xd;
      a.h[1] = pf.h[1] * xd;
      a.h[2] = pf.h[2] * xd;
      a.h[3] = pf.h[3] * xd;
      f16x8 b = *reinterpret_cast<const f16x8*>(bb + t * 1024 + rdoff);
      acc = __builtin_amdgcn_mfma_f32_32x32x16_f16(a.v, b, acc, 0, 0, 0);
    }
    if (ch < 7) {
      xb[(ch + 1) & 1][0] = cvt16(f0, f1);
      xb[(ch + 1) & 1][1] = cvt16(f2, f3);
    }
    __syncthreads();   // drains vmcnt (next chunk staged) + ends bb reads
  }

  // bias tail: i=128, X==1 -> A = pf
  {
    f16x8 b = *reinterpret_cast<const f16x8*>(Bs + rdoff);
    acc = __builtin_amdgcn_mfma_f32_32x32x16_f16(pf.v, b, acc, 0, 0, 0);
  }

  // C/D: col = lane&31, row = (q&3) + 8*(q>>2) + 4*(lane>>5)
#pragma unroll
  for (int q = 0; q < 16; ++q) {
    int r = (q & 3) + 8 * (q >> 2) + 4 * rh;
    part[((size_t)g * N_SAMPLES + (m0 + ms * 32 + r)) * O_OUT + jh * 32 + jl] =
        acc[q];
  }
}

// ---------------------------------------------------------------------------
// Kernel 4: sum 16 group partials + softmax over 64 outputs.
// ---------------------------------------------------------------------------
__global__ __launch_bounds__(256) void anfis_out(
    const float* __restrict__ part, float* __restrict__ out) {
  const int n = blockIdx.x * 4 + (threadIdx.x >> 6);
  const int lane = threadIdx.x & 63;
  const size_t stride = (size_t)N_SAMPLES * O_OUT;
  const float* p0 = part + (size_t)n * O_OUT + lane;
  float v = 0.f;
#pragma unroll
  for (int gg = 0; gg < 16; ++gg) v += p0[gg * stride];
  float mx = v;
#pragma unroll
  for (int off = 32; off; off >>= 1) mx = fmaxf(mx, __shfl_xor(mx, off, 64));
  float e = __expf(v - mx);
  float s = e;
#pragma unroll
  for (int off = 32; off; off >>= 1) s += __shfl_xor(s, off, 64);
  out[(size_t)n * O_OUT + lane] = e / s;
}

extern "C" void kernel_launch(void* const* d_in, const int* in_sizes, int n_in,
                              void* d_out, int out_size, void* d_ws, size_t ws_size,
                              hipStream_t stream) {
  const float* X       = (const float*)d_in[0];
  const float* centers = (const float*)d_in[1];
  const float* sigmas  = (const float*)d_in[2];
  const float* coeffs  = (const float*)d_in[3];
  float* out = (float*)d_out;

  float* part = (float*)d_ws;                                    // 16.78 MB
  f16*   Cp3  = (f16*)(part + (size_t)NG16 * N_SAMPLES * O_OUT);
  f16*   Bext = Cp3 + (size_t)NG16 * CP3_I * 1024;               // 4.72 MB
  f16*   P    = Bext + (size_t)100 * 256 * 8;                    // 400 KB / 2 MB

  anfis_prep_all<<<1088 + 128, 256, 0, stream>>>(coeffs, centers, sigmas, Cp3, Bext);
  anfis_s16n<<<N_SAMPLES / 16, 512, 0, stream>>>(X, Bext, P);
  anfis_rules32<<<512, 512, 0, stream>>>(X, P, Cp3, part);
  anfis_out<<<N_SAMPLES / 4, 256, 0, stream>>>(part, out);
}